// Round 3
// baseline (164.678 us; speedup 1.0000x reference)
//
#include <hip/hip_runtime.h>

static constexpr float F_IOU_TR   = 0.3f;
static constexpr float F_SCORE_TR = 0.0f;
static constexpr float F_EPS      = 1e-7f;

// Pack (score, idx) into a u64 whose unsigned order == (score asc, idx desc).
// Scores are >= 0 here, so the raw float bit pattern is monotone. ~idx makes
// the SMALLER index win on score ties (jnp.argmax = first occurrence).
__device__ __forceinline__ unsigned long long pack_cand(float score, unsigned int idx) {
    return ((unsigned long long)__float_as_uint(score) << 32) |
           (unsigned long long)(~idx);
}

__device__ __forceinline__ unsigned int unpack_idx(unsigned long long p) {
    return ~(unsigned int)(p & 0xFFFFFFFFull);
}

// Wave(64) shuffle reduce + 4-wave LDS reduce, then one atomicMax per class.
__device__ __forceinline__ void block_reduce_max2(unsigned long long b0,
                                                  unsigned long long b1,
                                                  unsigned long long* dst0,
                                                  unsigned long long* dst1) {
    __shared__ unsigned long long smem[4][2];
#pragma unroll
    for (int off = 32; off > 0; off >>= 1) {
        unsigned long long o0 = __shfl_down(b0, (unsigned)off, 64);
        unsigned long long o1 = __shfl_down(b1, (unsigned)off, 64);
        if (o0 > b0) b0 = o0;
        if (o1 > b1) b1 = o1;
    }
    const int wave = threadIdx.x >> 6;
    const int lane = threadIdx.x & 63;
    if (lane == 0) { smem[wave][0] = b0; smem[wave][1] = b1; }
    __syncthreads();
    if (threadIdx.x == 0) {
        unsigned long long m0 = smem[0][0], m1 = smem[0][1];
#pragma unroll
        for (int w = 1; w < 4; ++w) {
            if (smem[w][0] > m0) m0 = smem[w][0];
            if (smem[w][1] > m1) m1 = smem[w][1];
        }
        atomicMax(dst0, m0);
        atomicMax(dst1, m1);
    }
}

// ---------------- Pass 1 ----------------
// Stream the ENTIRE array as unit-stride float4 (copy-ubench shape): each
// thread owns 8 float4s at lane-contiguous addresses base + i*256. All 32
// floats are kept live (dummy sum + asm keep-alive) so the compiler emits 8
// full dwordx4 loads and keeps them all in flight. Even tids always hold row
// fronts (score, cls, x1, y1); odd tids' loads warm L2/L3 for pass 2.
static constexpr int P1_ELEMS = 8;                 // float4s per thread
static constexpr int P1_CHUNK = 256 * P1_ELEMS;    // float4s per block

__global__ __launch_bounds__(256) void nms_pass1(const float4* __restrict__ v, int M,
                                                 unsigned long long* __restrict__ ws) {
    unsigned long long b0 = 0ull, b1 = 0ull;
    const int base = blockIdx.x * P1_CHUNK + threadIdx.x;
    const bool front = !(threadIdx.x & 1);          // parity uniform per thread
    float keep = 0.0f;

    if (base + (P1_ELEMS - 1) * 256 < M && (blockIdx.x + 1) * P1_CHUNK <= M) {
        float4 q0 = v[base + 0 * 256];
        float4 q1 = v[base + 1 * 256];
        float4 q2 = v[base + 2 * 256];
        float4 q3 = v[base + 3 * 256];
        float4 q4 = v[base + 4 * 256];
        float4 q5 = v[base + 5 * 256];
        float4 q6 = v[base + 6 * 256];
        float4 q7 = v[base + 7 * 256];
        // Keep every component live: forces full dwordx4 loads, all in flight.
        keep = (q0.x + q0.y + q0.z + q0.w) + (q1.x + q1.y + q1.z + q1.w)
             + (q2.x + q2.y + q2.z + q2.w) + (q3.x + q3.y + q3.z + q3.w)
             + (q4.x + q4.y + q4.z + q4.w) + (q5.x + q5.y + q5.z + q5.w)
             + (q6.x + q6.y + q6.z + q6.w) + (q7.x + q7.y + q7.z + q7.w);
        if (front) {
            const float4 qs[8] = {q0, q1, q2, q3, q4, q5, q6, q7};
#pragma unroll
            for (int i = 0; i < 8; ++i) {
                const float s = qs[i].x, c = qs[i].y;
                if (s >= F_SCORE_TR) {
                    unsigned long long p =
                        pack_cand(s, (unsigned int)((base + i * 256) >> 1));
                    if (c < 0.5f) { if (p > b0) b0 = p; }
                    else          { if (p > b1) b1 = p; }
                }
            }
        }
    } else {
        for (int j = base; j < M; j += 256) {
            float4 q = v[j];
            keep += q.x + q.y + q.z + q.w;
            if (front && q.x >= F_SCORE_TR) {
                unsigned long long p = pack_cand(q.x, (unsigned int)(j >> 1));
                if (q.y < 0.5f) { if (p > b0) b0 = p; }
                else            { if (p > b1) b1 = p; }
            }
        }
    }
    asm volatile("" :: "v"(keep));   // rule #17: keep the loads, zero cost
    block_reduce_max2(b0, b1, &ws[0], &ws[1]);
}

// ---------------- Pass 2 ----------------
// Each thread owns 4 full rows (2 dwordx4 per row, stride-2 pattern whose two
// back-to-back instructions jointly cover every byte). All 8 loads issued
// before any IoU math -> 8 loads in flight. Data should be L3-resident.
static constexpr int P2_ROWS  = 4;                 // rows per thread
static constexpr int P2_CHUNK = 256 * P2_ROWS;     // rows per block

struct RefBoxes {
    float a0x, a0y, a0z, a1x, a1y, a1z, va;
    float c0x, c0y, c0z, c1x, c1y, c1z, vc;
};

__device__ __forceinline__ void p2_row(float4 r0, float4 r1, int row,
                                       const RefBoxes& R,
                                       unsigned long long& b0,
                                       unsigned long long& b1) {
    const float score = r0.x;
    const bool  is1   = (r0.y >= 0.5f);

    const float blx = is1 ? R.c0x : R.a0x;
    const float bly = is1 ? R.c0y : R.a0y;
    const float blz = is1 ? R.c0z : R.a0z;
    const float bhx = is1 ? R.c1x : R.a1x;
    const float bhy = is1 ? R.c1y : R.a1y;
    const float bhz = is1 ? R.c1z : R.a1z;
    const float v1  = is1 ? R.vc  : R.va;

    const float lox = fmaxf(blx, r0.z);
    const float loy = fmaxf(bly, r0.w);
    const float loz = fmaxf(blz, r1.x);
    const float hix = fminf(bhx, r1.y);
    const float hiy = fminf(bhy, r1.z);
    const float hiz = fminf(bhz, r1.w);
    const float inter = (fmaxf(hix - lox, 0.0f) * fmaxf(hiy - loy, 0.0f)) * fmaxf(hiz - loz, 0.0f);
    const float v2    = ((r1.y - r0.z) * (r1.z - r0.w)) * (r1.w - r1.x);
    const float iou   = inter / (v1 + v2 - inter + F_EPS);

    if (score >= F_SCORE_TR && iou <= F_IOU_TR) {
        unsigned long long p = pack_cand(score, (unsigned int)row);
        if (is1) { if (p > b1) b1 = p; }
        else     { if (p > b0) b0 = p; }
    }
}

__global__ __launch_bounds__(256) void nms_pass2(const float* __restrict__ res,
                                                 const float4* __restrict__ v, int N,
                                                 unsigned long long* __restrict__ ws) {
    const unsigned int ia = unpack_idx(ws[0]);
    const unsigned int ic = unpack_idx(ws[1]);
    const float* pa = res + (size_t)ia * 8 + 2;
    const float* pc = res + (size_t)ic * 8 + 2;
    RefBoxes R;
    R.a0x = pa[0]; R.a0y = pa[1]; R.a0z = pa[2]; R.a1x = pa[3]; R.a1y = pa[4]; R.a1z = pa[5];
    R.c0x = pc[0]; R.c0y = pc[1]; R.c0z = pc[2]; R.c1x = pc[3]; R.c1y = pc[4]; R.c1z = pc[5];
    R.va = ((R.a1x - R.a0x) * (R.a1y - R.a0y)) * (R.a1z - R.a0z);
    R.vc = ((R.c1x - R.c0x) * (R.c1y - R.c0y)) * (R.c1z - R.c0z);

    unsigned long long b0 = 0ull, b1 = 0ull;
    const int base = blockIdx.x * P2_CHUNK + threadIdx.x;

    if ((blockIdx.x + 1) * P2_CHUNK <= N) {
        const int r0i = base, r1i = base + 256, r2i = base + 512, r3i = base + 768;
        float4 f0 = v[2 * r0i], g0 = v[2 * r0i + 1];
        float4 f1 = v[2 * r1i], g1 = v[2 * r1i + 1];
        float4 f2 = v[2 * r2i], g2 = v[2 * r2i + 1];
        float4 f3 = v[2 * r3i], g3 = v[2 * r3i + 1];
        p2_row(f0, g0, r0i, R, b0, b1);
        p2_row(f1, g1, r1i, R, b0, b1);
        p2_row(f2, g2, r2i, R, b0, b1);
        p2_row(f3, g3, r3i, R, b0, b1);
    } else {
        for (int r = base; r < N; r += 256) {
            float4 f = v[2 * r], g = v[2 * r + 1];
            p2_row(f, g, r, R, b0, b1);
        }
    }
    block_reduce_max2(b0, b1, &ws[2], &ws[3]);
}

// Output rows: [c0:i0, c0:i1, c1:i0, c1:i1] x 8 cols = 32 floats.
__global__ void nms_write(const float* __restrict__ res,
                          const unsigned long long* __restrict__ ws,
                          float* __restrict__ out) {
    const int t = threadIdx.x;
    if (t >= 32) return;
    const int row  = t >> 3;
    const int col  = t & 7;
    const int slot = (row == 0) ? 0 : (row == 1) ? 2 : (row == 2) ? 1 : 3;
    const unsigned int idx = unpack_idx(ws[slot]);
    out[t] = res[(size_t)idx * 8 + col];
}

extern "C" void kernel_launch(void* const* d_in, const int* in_sizes, int n_in,
                              void* d_out, int out_size, void* d_ws, size_t ws_size,
                              hipStream_t stream) {
    const float* res = (const float*)d_in[0];
    const float4* v = (const float4*)d_in[0];
    const int N = in_sizes[0] / 8;
    const int M = N * 2;                      // number of float4s
    unsigned long long* ws = (unsigned long long*)d_ws;

    // ws[0..1]: per-class packed argmax (pass 1); ws[2..3]: post-NMS argmax (pass 2).
    hipMemsetAsync(d_ws, 0, 4 * sizeof(unsigned long long), stream);

    const int b1 = (M + P1_CHUNK - 1) / P1_CHUNK;
    const int b2 = (N + P2_CHUNK - 1) / P2_CHUNK;

    nms_pass1<<<b1, 256, 0, stream>>>(v, M, ws);
    nms_pass2<<<b2, 256, 0, stream>>>(res, v, N, ws);
    nms_write<<<1, 64, 0, stream>>>(res, ws, (float*)d_out);
}